// Round 12
// baseline (225.178 us; speedup 1.0000x reference)
//
#include <hip/hip_runtime.h>

// Inverse 3D DWT (DB4, periodization), (4,256,256,256) fp32.
// pass 1: axis-1 streaming transform, x -> ws (scalar, dense-row-coverage grid,
//         NT loads of x; measured ~6.1 TB/s, at roofline)
// pass 2: fused axis-2 + axis-3 per (b,d1) slice, ws -> out.
//         Tile 32 (d2) x 256 (full d3). global_load_lds staging; halo LDS
//         layout (stride 264) for aligned axis-3 vector reads; y0/y1 computed
//         as packed float2 -> v_pk_fma_f32 (halves FMA issue count).
// Polyphase: y[2m]   = sum_j s[(m+j-3)&127]*a[j] + w[..]*c[j]
//            y[2m+1] = sum_j s[(m+j-3)&127]*b[j] + w[..]*d[j]
// a[j]=h[6-2j], b[j]=h[7-2j], c[j]=h[2j+1], d[j]=-h[2j].
// NOTE: FILT_DECL owns identifiers a0..a3,b0..b3,c0..c3,d0..d3.

typedef float f32x2 __attribute__((ext_vector_type(2)));

#define FILT_DECL(h)                                          \
  const float a0 = h[6], a1 = h[4], a2 = h[2], a3 = h[0];     \
  const float b0 = h[7], b1 = h[5], b2 = h[3], b3 = h[1];     \
  const float c0 = h[1], c1 = h[3], c2 = h[5], c3 = h[7];     \
  const float d0 = -h[0], d1 = -h[2], d2 = -h[4], d3 = -h[6];

#define Y0(s0,s1,s2,s3,w0,w1,w2,w3)                                        \
  fmaf(w3, c3, fmaf(w2, c2, fmaf(w1, c1, fmaf(w0, c0,                      \
  fmaf(s3, a3, fmaf(s2, a2, fmaf(s1, a1, s0 * a0)))))))
#define Y1(s0,s1,s2,s3,w0,w1,w2,w3)                                        \
  fmaf(w3, d3, fmaf(w2, d2, fmaf(w1, d1, fmaf(w0, d0,                      \
  fmaf(s3, b3, fmaf(s2, b2, fmaf(s1, b1, s0 * b0)))))))

// packed fma: acc.xy += splat(s) * k.xy   (lowers to v_pk_fma_f32)
#define PKFMA(s, k, acc) __builtin_elementwise_fma((f32x2){(s),(s)}, (k), (acc))

// global -> LDS direct DMA, 4 bytes per lane
__device__ __forceinline__ void gload_lds4(const float* g, float* l) {
  auto gp = reinterpret_cast<const __attribute__((address_space(1))) int*>(
      reinterpret_cast<uintptr_t>(g));
  auto lp = reinterpret_cast<__attribute__((address_space(3))) int*>(
      reinterpret_cast<uintptr_t>(l));
  __builtin_amdgcn_global_load_lds(gp, lp, 4, 0, 0);
}

// ---------------- pass 1: axis 1 (row stride 65536), scalar, in -> tmp ----
__global__ __launch_bounds__(256) void wav_axis1_s(const float* __restrict__ in,
                                                   float* __restrict__ tmp,
                                                   const float* __restrict__ h) {
  const int inner = blockIdx.x * 256 + threadIdx.x;
  const int m0 = blockIdx.y * 64;
  const size_t base = (size_t)blockIdx.z * (256u * 65536u) + (unsigned)inner;
  const float* __restrict__ ps = in + base;
  const float* __restrict__ pw = in + base + (size_t)128 * 65536;
  float* __restrict__ po = tmp + base;
  FILT_DECL(h)
  float s0 = __builtin_nontemporal_load(&ps[(size_t)((m0 - 3) & 127) * 65536]);
  float s1 = __builtin_nontemporal_load(&ps[(size_t)((m0 - 2) & 127) * 65536]);
  float s2 = __builtin_nontemporal_load(&ps[(size_t)((m0 - 1) & 127) * 65536]);
  float w0 = __builtin_nontemporal_load(&pw[(size_t)((m0 - 3) & 127) * 65536]);
  float w1 = __builtin_nontemporal_load(&pw[(size_t)((m0 - 2) & 127) * 65536]);
  float w2 = __builtin_nontemporal_load(&pw[(size_t)((m0 - 1) & 127) * 65536]);
  for (int m = m0; m < m0 + 64; ++m) {
    const float s3 = __builtin_nontemporal_load(&ps[(size_t)m * 65536]);
    const float w3 = __builtin_nontemporal_load(&pw[(size_t)m * 65536]);
    po[(size_t)(2 * m) * 65536] = Y0(s0, s1, s2, s3, w0, w1, w2, w3);
    po[(size_t)(2 * m + 1) * 65536] = Y1(s0, s1, s2, s3, w0, w1, w2, w3);
    s0 = s1; s1 = s2; s2 = s3;
    w0 = w1; w1 = w2; w2 = w3;
  }
}

// ---------------- pass 2: fused axes 2+3, halo layout + pk_fma ------------
#define LSTR 264
__global__ __launch_bounds__(512, 8) void wav_t23h(const float* __restrict__ tmp,
                                                   float* __restrict__ out,
                                                   const float* __restrict__ hg) {
  __shared__ __align__(16) float lb[38 * LSTR];  // 40.1 KB
  const int t = threadIdx.x;
  const int d2t = blockIdx.x;                    // 0..7 (32 d2-rows each)
  const size_t slice = blockIdx.y;               // b*256 + d1
  const float* __restrict__ src = tmp + slice * 65536;
  FILT_DECL(hg)
  const f32x2 AB0 = {a0, b0}, AB1 = {a1, b1}, AB2 = {a2, b2}, AB3 = {a3, b3};
  const f32x2 CD0 = {c0, d0}, CD1 = {c1, d1}, CD2 = {c2, d2}, CD3 = {c3, d3};
  const int mb2 = 16 * d2t - 3;

  // stage 38 rows x 256 cols via global_load_lds (wave-uniform base + lane*4;
  // a wave's 64-lane window never crosses the c=128 seam).
#pragma unroll
  for (int k = 0; k < 19; ++k) {
    const int e = t + 512 * k;
    const int i2 = e >> 8, c = e & 255;
    const int g2 = (i2 < 19) ? ((mb2 + i2) & 127) : (128 + ((mb2 + i2 - 19) & 127));
    const int phys = c + ((c < 128) ? 3 : 7);
    gload_lds4(src + (g2 << 8) + c, &lb[i2 * LSTR + phys]);
  }
  __syncthreads();

  // axis-2: 256 columns x 2 half-threads; col j = t>>1, pairs p0..p0+7.
  // Dead-slot in-place: pair p writes y0->row p, y1->row 19+p. Fence REQUIRED
  // (cross-lane overlap between the p0=0 and p0=8 halves of each column).
  {
    const int j = t >> 1, p0 = (t & 1) * 8;
    const int pj = j + ((j < 128) ? 3 : 7);
    float S[11], W[11];
#pragma unroll
    for (int i = 0; i < 11; ++i) S[i] = lb[(p0 + i) * LSTR + pj];
#pragma unroll
    for (int i = 0; i < 11; ++i) W[i] = lb[(19 + p0 + i) * LSTR + pj];
    asm volatile("" ::: "memory");               // all reads before any write
    const int hcol = (j >= 125 && j < 128) ? (j - 125)
                   : ((j >= 253) ? (j - 121) : -1);
#pragma unroll
    for (int q = 0; q < 8; ++q) {
      const int p = p0 + q;
      f32x2 acc = (f32x2){S[q], S[q]} * AB0;
      acc = PKFMA(S[q+1], AB1, acc);
      acc = PKFMA(S[q+2], AB2, acc);
      acc = PKFMA(S[q+3], AB3, acc);
      acc = PKFMA(W[q],   CD0, acc);
      acc = PKFMA(W[q+1], CD1, acc);
      acc = PKFMA(W[q+2], CD2, acc);
      acc = PKFMA(W[q+3], CD3, acc);
      lb[p * LSTR + pj] = acc.x;
      lb[(19 + p) * LSTR + pj] = acc.y;
      if (hcol >= 0) {
        lb[p * LSTR + hcol] = acc.x;
        lb[(19 + p) * LSTR + hcol] = acc.y;
      }
    }
  }
  __syncthreads();

  // axis-3: r = t>>4 (0..31 local d2 row), 8 pairs starting at m0 = 8*(t&15).
  // Local out row r lives at phys row (r&1 ? 19+(r>>1) : r>>1).
  // Halo layout -> contiguous aligned reads:
  //   S[i] = lb[prow + m0 + i], W[i] = lb[prow + 132 + m0 + i]
  const int r = t >> 4, m0 = (t & 15) * 8;
  const int prow = ((r & 1) ? (19 + (r >> 1)) : (r >> 1)) * LSTR;
  float S[11], W[11];
  {
    const float4 sa = *reinterpret_cast<const float4*>(&lb[prow + m0]);
    const float4 sb = *reinterpret_cast<const float4*>(&lb[prow + m0 + 4]);
    const float2 sc = *reinterpret_cast<const float2*>(&lb[prow + m0 + 8]);
    S[0]=sa.x; S[1]=sa.y; S[2]=sa.z; S[3]=sa.w;
    S[4]=sb.x; S[5]=sb.y; S[6]=sb.z; S[7]=sb.w;
    S[8]=sc.x; S[9]=sc.y; S[10]=lb[prow + m0 + 10];
    const float4 wa = *reinterpret_cast<const float4*>(&lb[prow + 132 + m0]);
    const float4 wb = *reinterpret_cast<const float4*>(&lb[prow + 132 + m0 + 4]);
    const float2 wc = *reinterpret_cast<const float2*>(&lb[prow + 132 + m0 + 8]);
    W[0]=wa.x; W[1]=wa.y; W[2]=wa.z; W[3]=wa.w;
    W[4]=wb.x; W[5]=wb.y; W[6]=wb.z; W[7]=wb.w;
    W[8]=wc.x; W[9]=wc.y; W[10]=lb[prow + 132 + m0 + 10];
  }
  float* __restrict__ dst = out + slice * 65536
      + (size_t)(32 * d2t + r) * 256 + 16 * (t & 15);
#pragma unroll
  for (int g = 0; g < 4; ++g) {
    f32x2 eA = (f32x2){S[2*g], S[2*g]} * AB0;
    eA = PKFMA(S[2*g+1], AB1, eA);
    eA = PKFMA(S[2*g+2], AB2, eA);
    eA = PKFMA(S[2*g+3], AB3, eA);
    eA = PKFMA(W[2*g],   CD0, eA);
    eA = PKFMA(W[2*g+1], CD1, eA);
    eA = PKFMA(W[2*g+2], CD2, eA);
    eA = PKFMA(W[2*g+3], CD3, eA);
    f32x2 eB = (f32x2){S[2*g+1], S[2*g+1]} * AB0;
    eB = PKFMA(S[2*g+2], AB1, eB);
    eB = PKFMA(S[2*g+3], AB2, eB);
    eB = PKFMA(S[2*g+4], AB3, eB);
    eB = PKFMA(W[2*g+1], CD0, eB);
    eB = PKFMA(W[2*g+2], CD1, eB);
    eB = PKFMA(W[2*g+3], CD2, eB);
    eB = PKFMA(W[2*g+4], CD3, eB);
    *reinterpret_cast<float4*>(dst + 4 * g) = make_float4(eA.x, eA.y, eB.x, eB.y);
  }
}

// ================= fallback 3-pass (verified round 2) =================
__global__ __launch_bounds__(256) void wav_axis1(const float* __restrict__ in,
                                                 float* __restrict__ out,
                                                 const float* __restrict__ h) {
  const int inner = blockIdx.x * 256 + threadIdx.x;
  const int m0 = blockIdx.y * 64;
  const size_t base = (size_t)blockIdx.z * (256u * 65536u) + (unsigned)inner;
  const float* __restrict__ ps = in + base;
  const float* __restrict__ pw = in + base + (size_t)128 * 65536;
  float* __restrict__ po = out + base;
  FILT_DECL(h)
  float s0 = ps[(size_t)((m0 - 3) & 127) * 65536];
  float s1 = ps[(size_t)((m0 - 2) & 127) * 65536];
  float s2 = ps[(size_t)((m0 - 1) & 127) * 65536];
  float w0 = pw[(size_t)((m0 - 3) & 127) * 65536];
  float w1 = pw[(size_t)((m0 - 2) & 127) * 65536];
  float w2 = pw[(size_t)((m0 - 1) & 127) * 65536];
  for (int m = m0; m < m0 + 64; ++m) {
    const float s3 = ps[(size_t)m * 65536];
    const float w3 = pw[(size_t)m * 65536];
    po[(size_t)(2 * m) * 65536] = Y0(s0, s1, s2, s3, w0, w1, w2, w3);
    po[(size_t)(2 * m + 1) * 65536] = Y1(s0, s1, s2, s3, w0, w1, w2, w3);
    s0 = s1; s1 = s2; s2 = s3;
    w0 = w1; w1 = w2; w2 = w3;
  }
}

__global__ __launch_bounds__(256) void wav_axis2(float* __restrict__ buf,
                                                 const float* __restrict__ h) {
  __shared__ float tile[256][32];
  const int t = threadIdx.x;
  const int c = t & 31;
  const int g = t >> 5;
  const size_t slice = (size_t)(blockIdx.x >> 3);
  const int col0 = (blockIdx.x & 7) * 32;
  float* __restrict__ p = buf + slice * 65536 + col0;
#pragma unroll
  for (int i = 0; i < 32; ++i) {
    const int rr = i * 8 + g;
    tile[rr][c] = p[rr * 256 + c];
  }
  __syncthreads();
  FILT_DECL(h)
  const int m0 = g * 16;
  float s0 = tile[(m0 - 3) & 127][c];
  float s1 = tile[(m0 - 2) & 127][c];
  float s2 = tile[(m0 - 1) & 127][c];
  float w0 = tile[128 + ((m0 - 3) & 127)][c];
  float w1 = tile[128 + ((m0 - 2) & 127)][c];
  float w2 = tile[128 + ((m0 - 1) & 127)][c];
#pragma unroll
  for (int m = m0; m < m0 + 16; ++m) {
    const float s3 = tile[m][c];
    const float w3 = tile[128 + m][c];
    p[(2 * m) * 256 + c] = Y0(s0, s1, s2, s3, w0, w1, w2, w3);
    p[(2 * m + 1) * 256 + c] = Y1(s0, s1, s2, s3, w0, w1, w2, w3);
    s0 = s1; s1 = s2; s2 = s3;
    w0 = w1; w1 = w2; w2 = w3;
  }
}

__global__ __launch_bounds__(256) void wav_axis3(float* __restrict__ buf,
                                                 const float* __restrict__ h) {
  __shared__ float tile[512];
  const int t = threadIdx.x;
  float* __restrict__ p = buf + (size_t)blockIdx.x * 512;
  tile[t] = p[t];
  tile[256 + t] = p[256 + t];
  __syncthreads();
  FILT_DECL(h)
  const int rr = t >> 7;
  const int m = t & 127;
  const float* __restrict__ line = tile + rr * 256;
  const float s0 = line[(m - 3) & 127];
  const float s1 = line[(m - 2) & 127];
  const float s2 = line[(m - 1) & 127];
  const float s3 = line[m];
  const float w0 = line[128 + ((m - 3) & 127)];
  const float w1 = line[128 + ((m - 2) & 127)];
  const float w2 = line[128 + ((m - 1) & 127)];
  const float w3 = line[128 + m];
  float2 y;
  y.x = Y0(s0, s1, s2, s3, w0, w1, w2, w3);
  y.y = Y1(s0, s1, s2, s3, w0, w1, w2, w3);
  *reinterpret_cast<float2*>(p + rr * 256 + 2 * m) = y;
}

extern "C" void kernel_launch(void* const* d_in, const int* in_sizes, int n_in,
                              void* d_out, int out_size, void* d_ws, size_t ws_size,
                              hipStream_t stream) {
  const float* x = (const float*)d_in[0];
  const float* h = (const float*)d_in[1];
  float* out = (float*)d_out;
  const size_t need = (size_t)4 * 256 * 256 * 256 * 4;   // 268 MB intermediate

  if (ws_size >= need) {
    float* tmp = (float*)d_ws;
    wav_axis1_s<<<dim3(256, 2, 4), 256, 0, stream>>>(x, tmp, h);
    wav_t23h<<<dim3(8, 1024), 512, 0, stream>>>(tmp, out, h);
  } else {
    wav_axis1<<<dim3(256, 2, 4), 256, 0, stream>>>(x, out, h);
    wav_axis2<<<dim3(8192), 256, 0, stream>>>(out, h);
    wav_axis3<<<dim3(131072), 256, 0, stream>>>(out, h);
  }
}

// Round 13
// 220.666 us; speedup vs baseline: 1.0204x; 1.0204x over previous
//
#include <hip/hip_runtime.h>

// Inverse 3D DWT (DB4, periodization), (4,256,256,256) fp32.
// pass 1: axis-1 streaming transform, x -> ws (scalar, dense-row grid, NT loads;
//         measured ~6.1 TB/s, at roofline)
// pass 2: fused axis-2 + axis-3, tile 16 (d2) x 256 (d3), 256 threads,
//         22x264 LDS (23.2 KB -> 7 blocks/CU for phase stagger).
//         Staging: global_load_lds, i2=k (literal), c=t (fixed) -> 1 add/iter.
//         axis-2: one thread per column (8 pairs, no cross-lane hazard).
//         halo LDS layout for aligned axis-3 vector reads; pk_fma throughout.
// Polyphase: y[2m]   = sum_j s[(m+j-3)&127]*a[j] + w[..]*c[j]
//            y[2m+1] = sum_j s[(m+j-3)&127]*b[j] + w[..]*d[j]
// a[j]=h[6-2j], b[j]=h[7-2j], c[j]=h[2j+1], d[j]=-h[2j].

typedef float f32x2 __attribute__((ext_vector_type(2)));

#define FILT_DECL(h)                                          \
  const float a0 = h[6], a1 = h[4], a2 = h[2], a3 = h[0];     \
  const float b0 = h[7], b1 = h[5], b2 = h[3], b3 = h[1];     \
  const float c0 = h[1], c1 = h[3], c2 = h[5], c3 = h[7];     \
  const float d0 = -h[0], d1 = -h[2], d2 = -h[4], d3 = -h[6];

#define Y0(s0,s1,s2,s3,w0,w1,w2,w3)                                        \
  fmaf(w3, c3, fmaf(w2, c2, fmaf(w1, c1, fmaf(w0, c0,                      \
  fmaf(s3, a3, fmaf(s2, a2, fmaf(s1, a1, s0 * a0)))))))
#define Y1(s0,s1,s2,s3,w0,w1,w2,w3)                                        \
  fmaf(w3, d3, fmaf(w2, d2, fmaf(w1, d1, fmaf(w0, d0,                      \
  fmaf(s3, b3, fmaf(s2, b2, fmaf(s1, b1, s0 * b0)))))))

// packed fma: acc.xy += splat(s) * k.xy   (lowers to v_pk_fma_f32)
#define PKFMA(s, k, acc) __builtin_elementwise_fma((f32x2){(s),(s)}, (k), (acc))

// global -> LDS direct DMA, 4 bytes per lane
__device__ __forceinline__ void gload_lds4(const float* g, float* l) {
  auto gp = reinterpret_cast<const __attribute__((address_space(1))) int*>(
      reinterpret_cast<uintptr_t>(g));
  auto lp = reinterpret_cast<__attribute__((address_space(3))) int*>(
      reinterpret_cast<uintptr_t>(l));
  __builtin_amdgcn_global_load_lds(gp, lp, 4, 0, 0);
}

// ---------------- pass 1: axis 1 (row stride 65536), scalar, in -> tmp ----
__global__ __launch_bounds__(256) void wav_axis1_s(const float* __restrict__ in,
                                                   float* __restrict__ tmp,
                                                   const float* __restrict__ h) {
  const int inner = blockIdx.x * 256 + threadIdx.x;
  const int m0 = blockIdx.y * 64;
  const size_t base = (size_t)blockIdx.z * (256u * 65536u) + (unsigned)inner;
  const float* __restrict__ ps = in + base;
  const float* __restrict__ pw = in + base + (size_t)128 * 65536;
  float* __restrict__ po = tmp + base;
  FILT_DECL(h)
  float s0 = __builtin_nontemporal_load(&ps[(size_t)((m0 - 3) & 127) * 65536]);
  float s1 = __builtin_nontemporal_load(&ps[(size_t)((m0 - 2) & 127) * 65536]);
  float s2 = __builtin_nontemporal_load(&ps[(size_t)((m0 - 1) & 127) * 65536]);
  float w0 = __builtin_nontemporal_load(&pw[(size_t)((m0 - 3) & 127) * 65536]);
  float w1 = __builtin_nontemporal_load(&pw[(size_t)((m0 - 2) & 127) * 65536]);
  float w2 = __builtin_nontemporal_load(&pw[(size_t)((m0 - 1) & 127) * 65536]);
  for (int m = m0; m < m0 + 64; ++m) {
    const float s3 = __builtin_nontemporal_load(&ps[(size_t)m * 65536]);
    const float w3 = __builtin_nontemporal_load(&pw[(size_t)m * 65536]);
    po[(size_t)(2 * m) * 65536] = Y0(s0, s1, s2, s3, w0, w1, w2, w3);
    po[(size_t)(2 * m + 1) * 65536] = Y1(s0, s1, s2, s3, w0, w1, w2, w3);
    s0 = s1; s1 = s2; s2 = s3;
    w0 = w1; w1 = w2; w2 = w3;
  }
}

// ---------------- pass 2: fused axes 2+3, 16-row tile ---------------------
// LDS rows 0..10 = s (11 = 8 pairs + 3 halo), 11..21 = w.
// cols: [s-halo 0..2 | s 3..130 | pad | w-halo 132..134 | w 135..262]
#define LSTR 264
__global__ __launch_bounds__(256, 7) void wav_t23s(const float* __restrict__ tmp,
                                                   float* __restrict__ out,
                                                   const float* __restrict__ hg) {
  __shared__ __align__(16) float lb[22 * LSTR];  // 23.2 KB -> 7 blocks/CU
  const int t = threadIdx.x;
  const int d2t = blockIdx.x;                    // 0..15 (16 d2-rows each)
  const size_t slice = blockIdx.y;               // b*256 + d1
  const float* __restrict__ src = tmp + slice * 65536;
  FILT_DECL(hg)
  const f32x2 AB0 = {a0, b0}, AB1 = {a1, b1}, AB2 = {a2, b2}, AB3 = {a3, b3};
  const f32x2 CD0 = {c0, d0}, CD1 = {c1, d1}, CD2 = {c2, d2}, CD3 = {c3, d3};
  const int mb2 = 8 * d2t - 3;

  // stage 22 rows x 256 cols; c = t (fixed), i2 = k (literal) -> addr math
  // is one 64-bit add per row. Wave window never crosses the c=128 seam.
  {
    const int phys = t + ((t < 128) ? 3 : 7);
#pragma unroll
    for (int k = 0; k < 11; ++k) {               // s rows
      const int g2 = (mb2 + k) & 127;
      gload_lds4(src + (g2 << 8) + t, &lb[k * LSTR + phys]);
    }
#pragma unroll
    for (int k = 0; k < 11; ++k) {               // w rows
      const int g2 = 128 + ((mb2 + k) & 127);
      gload_lds4(src + (g2 << 8) + t, &lb[(11 + k) * LSTR + phys]);
    }
  }
  __syncthreads();

  // axis-2: one thread per column j=t; 8 pairs. Dead-slot in place:
  // pair p reads s rows p..p+3 / w rows p..p+3, writes y0->row p, y1->row 11+p.
  // Entire column owned by one thread -> no cross-lane hazard.
  {
    const int pj = t + ((t < 128) ? 3 : 7);
    float S[11], W[11];
#pragma unroll
    for (int i = 0; i < 11; ++i) S[i] = lb[i * LSTR + pj];
#pragma unroll
    for (int i = 0; i < 11; ++i) W[i] = lb[(11 + i) * LSTR + pj];
    // transformed cols 125..127 / 253..255 duplicated into halos
    const int hcol = (t >= 125 && t < 128) ? (t - 125)
                   : ((t >= 253) ? (t - 121) : -1);
#pragma unroll
    for (int q = 0; q < 8; ++q) {
      f32x2 acc = (f32x2){S[q], S[q]} * AB0;
      acc = PKFMA(S[q+1], AB1, acc);
      acc = PKFMA(S[q+2], AB2, acc);
      acc = PKFMA(S[q+3], AB3, acc);
      acc = PKFMA(W[q],   CD0, acc);
      acc = PKFMA(W[q+1], CD1, acc);
      acc = PKFMA(W[q+2], CD2, acc);
      acc = PKFMA(W[q+3], CD3, acc);
      lb[q * LSTR + pj] = acc.x;
      lb[(11 + q) * LSTR + pj] = acc.y;
      if (hcol >= 0) {
        lb[q * LSTR + hcol] = acc.x;
        lb[(11 + q) * LSTR + hcol] = acc.y;
      }
    }
  }
  __syncthreads();

  // axis-3: r = t>>4 (0..15 local d2 row), 8 pairs starting m0 = 8*(t&15).
  // Local row r -> phys row (r&1 ? 11+(r>>1) : r>>1). Halo layout ->
  // contiguous aligned reads: S[i]=lb[prow+m0+i], W[i]=lb[prow+132+m0+i].
  const int r = t >> 4, m0 = (t & 15) * 8;
  const int prow = ((r & 1) ? (11 + (r >> 1)) : (r >> 1)) * LSTR;
  float S[11], W[11];
  {
    const float4 sa = *reinterpret_cast<const float4*>(&lb[prow + m0]);
    const float4 sb = *reinterpret_cast<const float4*>(&lb[prow + m0 + 4]);
    const float2 sc = *reinterpret_cast<const float2*>(&lb[prow + m0 + 8]);
    S[0]=sa.x; S[1]=sa.y; S[2]=sa.z; S[3]=sa.w;
    S[4]=sb.x; S[5]=sb.y; S[6]=sb.z; S[7]=sb.w;
    S[8]=sc.x; S[9]=sc.y; S[10]=lb[prow + m0 + 10];
    const float4 wa = *reinterpret_cast<const float4*>(&lb[prow + 132 + m0]);
    const float4 wb = *reinterpret_cast<const float4*>(&lb[prow + 132 + m0 + 4]);
    const float2 wc = *reinterpret_cast<const float2*>(&lb[prow + 132 + m0 + 8]);
    W[0]=wa.x; W[1]=wa.y; W[2]=wa.z; W[3]=wa.w;
    W[4]=wb.x; W[5]=wb.y; W[6]=wb.z; W[7]=wb.w;
    W[8]=wc.x; W[9]=wc.y; W[10]=lb[prow + 132 + m0 + 10];
  }
  float* __restrict__ dst = out + slice * 65536
      + (size_t)(16 * d2t + r) * 256 + 16 * (t & 15);
#pragma unroll
  for (int g = 0; g < 4; ++g) {
    f32x2 eA = (f32x2){S[2*g], S[2*g]} * AB0;
    eA = PKFMA(S[2*g+1], AB1, eA);
    eA = PKFMA(S[2*g+2], AB2, eA);
    eA = PKFMA(S[2*g+3], AB3, eA);
    eA = PKFMA(W[2*g],   CD0, eA);
    eA = PKFMA(W[2*g+1], CD1, eA);
    eA = PKFMA(W[2*g+2], CD2, eA);
    eA = PKFMA(W[2*g+3], CD3, eA);
    f32x2 eB = (f32x2){S[2*g+1], S[2*g+1]} * AB0;
    eB = PKFMA(S[2*g+2], AB1, eB);
    eB = PKFMA(S[2*g+3], AB2, eB);
    eB = PKFMA(S[2*g+4], AB3, eB);
    eB = PKFMA(W[2*g+1], CD0, eB);
    eB = PKFMA(W[2*g+2], CD1, eB);
    eB = PKFMA(W[2*g+3], CD2, eB);
    eB = PKFMA(W[2*g+4], CD3, eB);
    *reinterpret_cast<float4*>(dst + 4 * g) = make_float4(eA.x, eA.y, eB.x, eB.y);
  }
}

// ================= fallback 3-pass (verified round 2) =================
__global__ __launch_bounds__(256) void wav_axis1(const float* __restrict__ in,
                                                 float* __restrict__ out,
                                                 const float* __restrict__ h) {
  const int inner = blockIdx.x * 256 + threadIdx.x;
  const int m0 = blockIdx.y * 64;
  const size_t base = (size_t)blockIdx.z * (256u * 65536u) + (unsigned)inner;
  const float* __restrict__ ps = in + base;
  const float* __restrict__ pw = in + base + (size_t)128 * 65536;
  float* __restrict__ po = out + base;
  FILT_DECL(h)
  float s0 = ps[(size_t)((m0 - 3) & 127) * 65536];
  float s1 = ps[(size_t)((m0 - 2) & 127) * 65536];
  float s2 = ps[(size_t)((m0 - 1) & 127) * 65536];
  float w0 = pw[(size_t)((m0 - 3) & 127) * 65536];
  float w1 = pw[(size_t)((m0 - 2) & 127) * 65536];
  float w2 = pw[(size_t)((m0 - 1) & 127) * 65536];
  for (int m = m0; m < m0 + 64; ++m) {
    const float s3 = ps[(size_t)m * 65536];
    const float w3 = pw[(size_t)m * 65536];
    po[(size_t)(2 * m) * 65536] = Y0(s0, s1, s2, s3, w0, w1, w2, w3);
    po[(size_t)(2 * m + 1) * 65536] = Y1(s0, s1, s2, s3, w0, w1, w2, w3);
    s0 = s1; s1 = s2; s2 = s3;
    w0 = w1; w1 = w2; w2 = w3;
  }
}

__global__ __launch_bounds__(256) void wav_axis2(float* __restrict__ buf,
                                                 const float* __restrict__ h) {
  __shared__ float tile[256][32];
  const int t = threadIdx.x;
  const int c = t & 31;
  const int g = t >> 5;
  const size_t slice = (size_t)(blockIdx.x >> 3);
  const int col0 = (blockIdx.x & 7) * 32;
  float* __restrict__ p = buf + slice * 65536 + col0;
#pragma unroll
  for (int i = 0; i < 32; ++i) {
    const int rr = i * 8 + g;
    tile[rr][c] = p[rr * 256 + c];
  }
  __syncthreads();
  FILT_DECL(h)
  const int m0 = g * 16;
  float s0 = tile[(m0 - 3) & 127][c];
  float s1 = tile[(m0 - 2) & 127][c];
  float s2 = tile[(m0 - 1) & 127][c];
  float w0 = tile[128 + ((m0 - 3) & 127)][c];
  float w1 = tile[128 + ((m0 - 2) & 127)][c];
  float w2 = tile[128 + ((m0 - 1) & 127)][c];
#pragma unroll
  for (int m = m0; m < m0 + 16; ++m) {
    const float s3 = tile[m][c];
    const float w3 = tile[128 + m][c];
    p[(2 * m) * 256 + c] = Y0(s0, s1, s2, s3, w0, w1, w2, w3);
    p[(2 * m + 1) * 256 + c] = Y1(s0, s1, s2, s3, w0, w1, w2, w3);
    s0 = s1; s1 = s2; s2 = s3;
    w0 = w1; w1 = w2; w2 = w3;
  }
}

__global__ __launch_bounds__(256) void wav_axis3(float* __restrict__ buf,
                                                 const float* __restrict__ h) {
  __shared__ float tile[512];
  const int t = threadIdx.x;
  float* __restrict__ p = buf + (size_t)blockIdx.x * 512;
  tile[t] = p[t];
  tile[256 + t] = p[256 + t];
  __syncthreads();
  FILT_DECL(h)
  const int rr = t >> 7;
  const int m = t & 127;
  const float* __restrict__ line = tile + rr * 256;
  const float s0 = line[(m - 3) & 127];
  const float s1 = line[(m - 2) & 127];
  const float s2 = line[(m - 1) & 127];
  const float s3 = line[m];
  const float w0 = line[128 + ((m - 3) & 127)];
  const float w1 = line[128 + ((m - 2) & 127)];
  const float w2 = line[128 + ((m - 1) & 127)];
  const float w3 = line[128 + m];
  float2 y;
  y.x = Y0(s0, s1, s2, s3, w0, w1, w2, w3);
  y.y = Y1(s0, s1, s2, s3, w0, w1, w2, w3);
  *reinterpret_cast<float2*>(p + rr * 256 + 2 * m) = y;
}

extern "C" void kernel_launch(void* const* d_in, const int* in_sizes, int n_in,
                              void* d_out, int out_size, void* d_ws, size_t ws_size,
                              hipStream_t stream) {
  const float* x = (const float*)d_in[0];
  const float* h = (const float*)d_in[1];
  float* out = (float*)d_out;
  const size_t need = (size_t)4 * 256 * 256 * 256 * 4;   // 268 MB intermediate

  if (ws_size >= need) {
    float* tmp = (float*)d_ws;
    wav_axis1_s<<<dim3(256, 2, 4), 256, 0, stream>>>(x, tmp, h);
    wav_t23s<<<dim3(16, 1024), 256, 0, stream>>>(tmp, out, h);
  } else {
    wav_axis1<<<dim3(256, 2, 4), 256, 0, stream>>>(x, out, h);
    wav_axis2<<<dim3(8192), 256, 0, stream>>>(out, h);
    wav_axis3<<<dim3(131072), 256, 0, stream>>>(out, h);
  }
}